// Round 3
// baseline (623.622 us; speedup 1.0000x reference)
//
#include <hip/hip_runtime.h>
#include <hip/hip_bf16.h>

// Problem constants (reference: WORLD_SIZE=8, M_LOCAL=1024, K=4096, N=4096)
#define M_TOTAL 8192
#define KDIM    4096
#define NDIM    4096

// GEMM tiling: 256x256 tile, BK=32, 512 threads (8 waves as 2M x 4N),
// per-wave output 128x64, 4-deep LDS ring, counted vmcnt pipeline,
// register-double-buffered fragments (NEW this round).
#define BM 256
#define BN 256
#define BK 32
#define NT (KDIM / BK)          // 128 K-tiles
#define AREG (BM * BK)          // 8192 elems = 16 KiB per buffer (A)
#define BREG (BN * BK)          // 8192 elems = 16 KiB per buffer (B)
#define BUFE (AREG + BREG)      // 16384 elems = 32 KiB per ring slot
// ring = 4 slots = 128 KiB dynamic LDS

typedef __bf16 bf16x8 __attribute__((ext_vector_type(8)));
typedef float  f32x4  __attribute__((ext_vector_type(4)));

// ---------------------------------------------------------------------------
// fp32 -> bf16 (RNE), 8 elems/thread, 16B stores; A and W in one launch
// (unchanged — isolates the GEMM change)
// ---------------------------------------------------------------------------
__device__ __forceinline__ unsigned short f32_to_bf16_rne(unsigned u) {
    unsigned r = u + 0x7fffu + ((u >> 16) & 1u);
    return (unsigned short)(r >> 16);
}

__device__ __forceinline__ void cvt8(const float* __restrict__ s,
                                     unsigned short* __restrict__ d) {
    const uint4* sp = (const uint4*)s;
    uint4 x = sp[0];
    uint4 y = sp[1];
    uint4 o;
    o.x = (unsigned)f32_to_bf16_rne(x.x) | ((unsigned)f32_to_bf16_rne(x.y) << 16);
    o.y = (unsigned)f32_to_bf16_rne(x.z) | ((unsigned)f32_to_bf16_rne(x.w) << 16);
    o.z = (unsigned)f32_to_bf16_rne(y.x) | ((unsigned)f32_to_bf16_rne(y.y) << 16);
    o.w = (unsigned)f32_to_bf16_rne(y.z) | ((unsigned)f32_to_bf16_rne(y.w) << 16);
    *(uint4*)d = o;
}

__global__ __launch_bounds__(256) void cvt_both(const float* __restrict__ A,
                                                unsigned short* __restrict__ Abf,
                                                long nA,
                                                const float* __restrict__ W,
                                                unsigned short* __restrict__ Wbf) {
    long i = ((long)blockIdx.x * 256 + threadIdx.x) * 8;
    if (i < nA) {
        cvt8(A + i, Abf + i);
    } else {
        long j = i - nA;
        cvt8(W + j, Wbf + j);
    }
}

// ---------------------------------------------------------------------------
// async global -> LDS, 16B per lane (wave-uniform LDS base + lane*16)
// ---------------------------------------------------------------------------
__device__ __forceinline__ void gload_lds16(const unsigned short* g, unsigned short* l) {
    __builtin_amdgcn_global_load_lds(
        (const __attribute__((address_space(1))) unsigned int*)g,
        (__attribute__((address_space(3))) unsigned int*)l,
        16, 0, 0);
}

// ---------------------------------------------------------------------------
// C[M,N] = A[M,K] * B[N,K]^T   (bf16 in, fp32 out)
//
// CHANGE THIS ROUND: register double-buffered fragments. Iter t issues the
// 12 ds_reads for tile t+1 (resident: vmcnt(4) retires it), then runs 32
// MFMAs on tile t's ALREADY-IN-REG fragments — no lgkm dependency inside the
// cluster, so LDS service of next-tile reads hides under ~1242cy of MFMA.
//
//   iter t:  s_waitcnt vmcnt(4)    // outstanding {t+1,t+2}=8 -> t+1 retired
//            s_barrier             // collectively: t+1 in LDS; all waves'
//                                  //   reads of tile t-1 done (lgkm0 below)
//            stage tile t+3 -> ring[(t+3)&3] == ring[(t-1)&3]  (safe)
//            ds_read 12 frags of tile t+1 from ring[(t+1)&3] -> F_next
//            sched_barrier(0)      // pin reads before the MFMA cluster
//            32 MFMA on F_cur (registers only; setprio-wrapped)
//            s_waitcnt lgkmcnt(0)  // F_next reads complete (had full MFMA
//                                  //   span); enables slot reuse next iter
//
// Prefetch distances: LDS slot staged 3 iters ahead (vmcnt ledger
// 4,...,4,4,0,-; never drains early); frag regs 1 iter ahead. Ping-pong
// frag sets (t&1) with 4x-unrolled loop -> all indices static (rule #20).
// ds_reads are compiler-emitted loads -> compiler inserts the lgkm waits
// before first consuming MFMA of iter t+1 (rule #18 does not apply).
//
// LDS chunk swizzle (unchanged, 0 conflicts measured): slot s of row r holds
// global 16B-chunk s ^ ((r>>1)&3); staging pre-swizzles the per-lane GLOBAL
// address so the LDS destination stays linear (global_load_lds requirement).
// ---------------------------------------------------------------------------
__global__ __launch_bounds__(512, 2) void gemm_bt(const unsigned short* __restrict__ A,
                                                  const unsigned short* __restrict__ B,
                                                  float* __restrict__ C) {
    extern __shared__ unsigned short smem[];

    const int tid  = threadIdx.x;
    const int wave = tid >> 6;
    const int lane = tid & 63;

    const int n0 = blockIdx.x * BN;
    const int m0 = blockIdx.y * BM;

    // ---- staging addresses (pre-swizzled global source chunk) ----
    const int rsub = tid >> 2;                          // 0..127
    const int cswz = (tid & 3) ^ ((tid >> 3) & 3);      // swizzled src chunk
    const unsigned short* pA0 = A + (size_t)(m0 + rsub)       * KDIM + cswz * 8;
    const unsigned short* pA1 = A + (size_t)(m0 + 128 + rsub) * KDIM + cswz * 8;
    const unsigned short* pB0 = B + (size_t)(n0 + rsub)       * KDIM + cswz * 8;
    const unsigned short* pB1 = B + (size_t)(n0 + 128 + rsub) * KDIM + cswz * 8;
    const int woff = wave * 512;   // wave slice (1 KiB) within a G::load

    // ---- read addressing (wave (wm,wn) owns a 128x64 output block) ----
    const int wm   = wave >> 2;    // 0..1
    const int wn   = wave & 3;     // 0..3
    const int quad = lane >> 4;    // 0..3  (K-chunk index of A/B operands)
    const int r    = lane & 15;    // m (A) / n (B) / col (C)
    const int sidx = (quad ^ ((r >> 1) & 3)) * 8;   // swizzled read offset

    int aoff[8], boff[4];
#pragma unroll
    for (int mi = 0; mi < 8; ++mi) aoff[mi] = (wm * 128 + mi * 16 + r) * BK + sidx;
#pragma unroll
    for (int ni = 0; ni < 4; ++ni) boff[ni] = (wn * 64 + ni * 16 + r) * BK + sidx;

    f32x4 acc[8][4] = {};
    bf16x8 aF0[8], bF0[4], aF1[8], bF1[4];   // ping-pong fragment sets

#define SAp(b) (smem + (b) * BUFE)
#define SBq(b) (smem + (b) * BUFE + AREG)
#define STAGE(TS, SB) do {                                                  \
        const size_t so_ = (size_t)(TS) * BK;                               \
        gload_lds16(pA0 + so_, SAp(SB) + woff);                             \
        gload_lds16(pA1 + so_, SAp(SB) + 4096 + woff);                      \
        gload_lds16(pB0 + so_, SBq(SB) + woff);                             \
        gload_lds16(pB1 + so_, SBq(SB) + 4096 + woff);                      \
    } while (0)

#define READF(RB, AF, BF) do {                                              \
        const unsigned short* baA_ = SAp(RB);                               \
        const unsigned short* baB_ = SBq(RB);                               \
        _Pragma("unroll")                                                   \
        for (int mi = 0; mi < 8; ++mi)                                      \
            AF[mi] = *(const bf16x8*)(baA_ + aoff[mi]);                     \
        _Pragma("unroll")                                                   \
        for (int ni = 0; ni < 4; ++ni)                                      \
            BF[ni] = *(const bf16x8*)(baB_ + boff[ni]);                     \
    } while (0)

#define MFMAC(AF, BF) do {                                                  \
        __builtin_amdgcn_s_setprio(1);                                      \
        _Pragma("unroll")                                                   \
        for (int mi = 0; mi < 8; ++mi)                                      \
            _Pragma("unroll")                                               \
            for (int ni = 0; ni < 4; ++ni)                                  \
                acc[mi][ni] = __builtin_amdgcn_mfma_f32_16x16x32_bf16(      \
                    AF[mi], BF[ni], acc[mi][ni], 0, 0, 0);                  \
        __builtin_amdgcn_s_setprio(0);                                      \
    } while (0)

// iter t: RBn=(t+1)&3 (read next tile's frags), SB=(t+3)&3 (stage target)
#define ITER(RBn, SB, VM, DOSTAGE, TS, AFc, BFc, AFn, BFn) do {             \
        asm volatile("s_waitcnt vmcnt(" #VM ")" ::: "memory");              \
        __builtin_amdgcn_s_barrier();                                       \
        asm volatile("" ::: "memory");                                      \
        if (DOSTAGE) STAGE(TS, SB);                                         \
        READF(RBn, AFn, BFn);                                               \
        __builtin_amdgcn_sched_barrier(0);                                  \
        MFMAC(AFc, BFc);                                                    \
        asm volatile("s_waitcnt lgkmcnt(0)" ::: "memory");                  \
    } while (0)

    // prologue: stage tiles 0,1,2 -> slots 0,1,2; preload frags(0) -> set0
    STAGE(0, 0);
    STAGE(1, 1);
    STAGE(2, 2);
    asm volatile("s_waitcnt vmcnt(8)" ::: "memory");   // tile 0 resident
    __builtin_amdgcn_s_barrier();
    asm volatile("" ::: "memory");
    READF(0, aF0, bF0);

    // main loop: t = 4g..4g+3, g = 0..30 (stages tiles 3..126)
    for (int g = 0; g < NT / 4 - 1; ++g) {
        const int t = g * 4;
        ITER(1, 3, 4, true, t + 3, aF0, bF0, aF1, bF1);   // t%4==0, cur=set0
        ITER(2, 0, 4, true, t + 4, aF1, bF1, aF0, bF0);   // t%4==1
        ITER(3, 1, 4, true, t + 5, aF0, bF0, aF1, bF1);   // t%4==2
        ITER(0, 2, 4, true, t + 6, aF1, bF1, aF0, bF0);   // t%4==3
    }
    // tail t=124..127: stage last tile at 124; vm ladder 4,4,0,-
    ITER(1, 3, 4, true, 127, aF0, bF0, aF1, bF1);         // t=124
    ITER(2, 0, 4, false, 0, aF1, bF1, aF0, bF0);          // t=125
    ITER(3, 1, 0, false, 0, aF0, bF0, aF1, bF1);          // t=126
    MFMAC(aF1, bF1);                                      // t=127 (regs only)

#undef ITER
#undef MFMAC
#undef READF
#undef STAGE
#undef SAp
#undef SBq

    // C/D layout: col = lane&15, row = quad*4 + reg  [verified m89/m91]
#pragma unroll
    for (int mi = 0; mi < 8; ++mi) {
        const int row = m0 + wm * 128 + mi * 16 + quad * 4;
#pragma unroll
        for (int ni = 0; ni < 4; ++ni) {
            const int col = n0 + wn * 64 + ni * 16 + r;
            float* p = C + (size_t)row * NDIM + col;
#pragma unroll
            for (int rr = 0; rr < 4; ++rr)
                p[(size_t)rr * NDIM] = acc[mi][ni][rr];
        }
    }
}

// ---------------------------------------------------------------------------
extern "C" void kernel_launch(void* const* d_in, const int* in_sizes, int n_in,
                              void* d_out, int out_size, void* d_ws, size_t ws_size,
                              hipStream_t stream) {
    const float* A = (const float*)d_in[0];   // [8,1024,4096] == [8192,4096]
    const float* W = (const float*)d_in[1];   // [4096,4096]  (N,K)
    float* out = (float*)d_out;               // [8192,4096] fp32

    unsigned short* Abf = (unsigned short*)d_ws;                       // 64 MiB
    unsigned short* Wbf = Abf + (size_t)M_TOTAL * KDIM;                // 32 MiB

    const long nA = (long)M_TOTAL * KDIM;     // 33,554,432
    const long nW = (long)NDIM * KDIM;        // 16,777,216
    const long nTot = nA + nW;

    cvt_both<<<(int)(nTot / 8 / 256), 256, 0, stream>>>(A, Abf, nA, W, Wbf);

    // 128 KiB dynamic LDS needs the attribute raised once (host-side call,
    // graph-capture safe: not a stream op)
    static bool attr_done = false;
    if (!attr_done) {
        hipFuncSetAttribute((const void*)gemm_bt,
                            hipFuncAttributeMaxDynamicSharedMemorySize, 128 * 1024);
        attr_done = true;
    }

    dim3 grid(NDIM / BN, M_TOTAL / BM);       // (16, 32) = 512 blocks
    gemm_bt<<<grid, 512, 128 * 1024, stream>>>(Abf, Wbf, out);
}

// Round 4
// 486.562 us; speedup vs baseline: 1.2817x; 1.2817x over previous
//
#include <hip/hip_runtime.h>
#include <hip/hip_bf16.h>

// Problem constants (reference: WORLD_SIZE=8, M_LOCAL=1024, K=4096, N=4096)
#define M_TOTAL 8192
#define KDIM    4096
#define NDIM    4096

// GEMM tiling: 256x256 tile, BK=32, 512 threads (8 waves as 2M x 4N),
// per-wave output 128x64, 4-deep LDS ring, counted vmcnt pipeline,
// 2 sub-phases per K-tile (m201 8-phase-equivalent rate).
#define BM 256
#define BN 256
#define BK 32
#define NT (KDIM / BK)          // 128 K-tiles
#define AREG (BM * BK)          // 8192 elems = 16 KiB per buffer (A)
#define BREG (BN * BK)          // 8192 elems = 16 KiB per buffer (B)
#define BUFE (AREG + BREG)      // 16384 elems = 32 KiB per ring slot
// ring = 4 slots = 128 KiB dynamic LDS

typedef __bf16 bf16x8 __attribute__((ext_vector_type(8)));
typedef float  f32x4  __attribute__((ext_vector_type(4)));

// ---------------------------------------------------------------------------
// fp32 -> bf16 (RNE), 8 elems/thread, 16B stores; A and W in one launch
// (unchanged — isolates the GEMM change)
// ---------------------------------------------------------------------------
__device__ __forceinline__ unsigned short f32_to_bf16_rne(unsigned u) {
    unsigned r = u + 0x7fffu + ((u >> 16) & 1u);
    return (unsigned short)(r >> 16);
}

__device__ __forceinline__ void cvt8(const float* __restrict__ s,
                                     unsigned short* __restrict__ d) {
    const uint4* sp = (const uint4*)s;
    uint4 x = sp[0];
    uint4 y = sp[1];
    uint4 o;
    o.x = (unsigned)f32_to_bf16_rne(x.x) | ((unsigned)f32_to_bf16_rne(x.y) << 16);
    o.y = (unsigned)f32_to_bf16_rne(x.z) | ((unsigned)f32_to_bf16_rne(x.w) << 16);
    o.z = (unsigned)f32_to_bf16_rne(y.x) | ((unsigned)f32_to_bf16_rne(y.y) << 16);
    o.w = (unsigned)f32_to_bf16_rne(y.z) | ((unsigned)f32_to_bf16_rne(y.w) << 16);
    *(uint4*)d = o;
}

__global__ __launch_bounds__(256) void cvt_both(const float* __restrict__ A,
                                                unsigned short* __restrict__ Abf,
                                                long nA,
                                                const float* __restrict__ W,
                                                unsigned short* __restrict__ Wbf) {
    long i = ((long)blockIdx.x * 256 + threadIdx.x) * 8;
    if (i < nA) {
        cvt8(A + i, Abf + i);
    } else {
        long j = i - nA;
        cvt8(W + j, Wbf + j);
    }
}

// ---------------------------------------------------------------------------
// async global -> LDS, 16B per lane (wave-uniform LDS base + lane*16)
// ---------------------------------------------------------------------------
__device__ __forceinline__ void gload_lds16(const unsigned short* g, unsigned short* l) {
    __builtin_amdgcn_global_load_lds(
        (const __attribute__((address_space(1))) unsigned int*)g,
        (__attribute__((address_space(3))) unsigned int*)l,
        16, 0, 0);
}

// ---------------------------------------------------------------------------
// C[M,N] = A[M,K] * B[N,K]^T   (bf16 in, fp32 out)
//
// CHANGE THIS ROUND (m201 phase schedule, reverting r3's spilling frag-dbuf):
// each K-tile is split into TWO phases of 16 MFMA. Per phase: issue ~8
// ds_reads -> barrier -> lgkmcnt(0) -> 16 MFMA (setprio) -> barrier.
// Reads are issued BEFORE the barrier: their LDS service overlaps the
// barrier-arrival spread, and early-released waves' MFMA clusters overlap
// late waves' LDS service (T3/T5 role-split). Frag regs: aFa[4]+aFb[4]+bF[4]
// = 12 bf16x8 — same budget as round 2, no spill.
//
//   tile t (slot rb=t&3):
//   phA: read bF[0..3], aFa[0..3] from rb; stage A-half(t+3);
//        bar; lgkm0; MFMA mi0-3; bar
//   phB: read aFb[0..3] from rb; stage B-half(t+3); vmcnt(8);
//        bar; lgkm0; MFMA mi4-7; bar
//
// Ledger (gload stream = [A(t+3) x2, B(t+3) x2] per tile, max 12 out):
//   - vmcnt(8) at t phB retires tile t+1's 4 gloads, >=1 barrier before
//     t+1 phA's reads -> collective LDS visibility holds.
//   - slot (t+3)&3 == (t-1)&3: all waves' reads of tile t-1 were lgkm0-
//     drained before t-1 phB's post-MFMA barrier; stages issue >=1 barrier
//     later -> no overwrite race.
//   - tail vm ladder: ..., 8 (t=124, stages 127), 4, 0, 0.
//
// LDS chunk swizzle (unchanged, 0 conflicts measured): slot s of row r holds
// global 16B-chunk s ^ ((r>>1)&3); staging pre-swizzles the per-lane GLOBAL
// address so the LDS destination stays linear (global_load_lds requirement).
// ---------------------------------------------------------------------------
__global__ __launch_bounds__(512, 2) void gemm_bt(const unsigned short* __restrict__ A,
                                                  const unsigned short* __restrict__ B,
                                                  float* __restrict__ C) {
    extern __shared__ unsigned short smem[];

    const int tid  = threadIdx.x;
    const int wave = tid >> 6;
    const int lane = tid & 63;

    const int n0 = blockIdx.x * BN;
    const int m0 = blockIdx.y * BM;

    // ---- staging addresses (pre-swizzled global source chunk) ----
    const int rsub = tid >> 2;                          // 0..127
    const int cswz = (tid & 3) ^ ((tid >> 3) & 3);      // swizzled src chunk
    const unsigned short* pA0 = A + (size_t)(m0 + rsub)       * KDIM + cswz * 8;
    const unsigned short* pA1 = A + (size_t)(m0 + 128 + rsub) * KDIM + cswz * 8;
    const unsigned short* pB0 = B + (size_t)(n0 + rsub)       * KDIM + cswz * 8;
    const unsigned short* pB1 = B + (size_t)(n0 + 128 + rsub) * KDIM + cswz * 8;
    const int woff = wave * 512;   // wave slice (1 KiB) within a G::load

    // ---- read addressing (wave (wm,wn) owns a 128x64 output block) ----
    const int wm   = wave >> 2;    // 0..1
    const int wn   = wave & 3;     // 0..3
    const int quad = lane >> 4;    // 0..3  (K-chunk index of A/B operands)
    const int r    = lane & 15;    // m (A) / n (B) / col (C)
    const int sidx = (quad ^ ((r >> 1) & 3)) * 8;   // swizzled read offset

    int aoff[8], boff[4];
#pragma unroll
    for (int mi = 0; mi < 8; ++mi) aoff[mi] = (wm * 128 + mi * 16 + r) * BK + sidx;
#pragma unroll
    for (int ni = 0; ni < 4; ++ni) boff[ni] = (wn * 64 + ni * 16 + r) * BK + sidx;

    f32x4 acc[8][4] = {};
    bf16x8 aFa[4], aFb[4], bF[4];   // 12 live frags (round-2 footprint)

#define SAp(b) (smem + (b) * BUFE)
#define SBq(b) (smem + (b) * BUFE + AREG)
#define STAGE(TS, SB) do {                                                  \
        const size_t so_ = (size_t)(TS) * BK;                               \
        gload_lds16(pA0 + so_, SAp(SB) + woff);                             \
        gload_lds16(pA1 + so_, SAp(SB) + 4096 + woff);                      \
        gload_lds16(pB0 + so_, SBq(SB) + woff);                             \
        gload_lds16(pB1 + so_, SBq(SB) + 4096 + woff);                      \
    } while (0)

#define TILE(RB, SB, VM, DOSTAGE, TS) do {                                  \
        /* ---------- phase A: bF + aFa reads, stage A-half, MFMA mi0-3 */  \
        _Pragma("unroll")                                                   \
        for (int ni = 0; ni < 4; ++ni)                                      \
            bF[ni] = *(const bf16x8*)(SBq(RB) + boff[ni]);                  \
        _Pragma("unroll")                                                   \
        for (int mi = 0; mi < 4; ++mi)                                      \
            aFa[mi] = *(const bf16x8*)(SAp(RB) + aoff[mi]);                 \
        if (DOSTAGE) {                                                      \
            const size_t so_ = (size_t)(TS) * BK;                           \
            gload_lds16(pA0 + so_, SAp(SB) + woff);                         \
            gload_lds16(pA1 + so_, SAp(SB) + 4096 + woff);                  \
        }                                                                   \
        asm volatile("" ::: "memory");                                      \
        __builtin_amdgcn_s_barrier();                                       \
        asm volatile("s_waitcnt lgkmcnt(0)" ::: "memory");                  \
        __builtin_amdgcn_s_setprio(1);                                      \
        _Pragma("unroll")                                                   \
        for (int mi = 0; mi < 4; ++mi)                                      \
            _Pragma("unroll")                                               \
            for (int ni = 0; ni < 4; ++ni)                                  \
                acc[mi][ni] = __builtin_amdgcn_mfma_f32_16x16x32_bf16(      \
                    aFa[mi], bF[ni], acc[mi][ni], 0, 0, 0);                 \
        __builtin_amdgcn_s_setprio(0);                                      \
        asm volatile("" ::: "memory");                                      \
        __builtin_amdgcn_s_barrier();                                       \
        asm volatile("" ::: "memory");                                      \
        /* ---------- phase B: aFb reads, stage B-half, vmcnt, MFMA mi4-7 */\
        _Pragma("unroll")                                                   \
        for (int mi = 0; mi < 4; ++mi)                                      \
            aFb[mi] = *(const bf16x8*)(SAp(RB) + aoff[4 + mi]);             \
        if (DOSTAGE) {                                                      \
            const size_t so_ = (size_t)(TS) * BK;                           \
            gload_lds16(pB0 + so_, SBq(SB) + woff);                         \
            gload_lds16(pB1 + so_, SBq(SB) + 4096 + woff);                  \
        }                                                                   \
        asm volatile("s_waitcnt vmcnt(" #VM ")" ::: "memory");              \
        __builtin_amdgcn_s_barrier();                                       \
        asm volatile("s_waitcnt lgkmcnt(0)" ::: "memory");                  \
        __builtin_amdgcn_s_setprio(1);                                      \
        _Pragma("unroll")                                                   \
        for (int mi = 0; mi < 4; ++mi)                                      \
            _Pragma("unroll")                                               \
            for (int ni = 0; ni < 4; ++ni)                                  \
                acc[4 + mi][ni] = __builtin_amdgcn_mfma_f32_16x16x32_bf16(  \
                    aFb[mi], bF[ni], acc[4 + mi][ni], 0, 0, 0);             \
        __builtin_amdgcn_s_setprio(0);                                      \
        asm volatile("" ::: "memory");                                      \
        __builtin_amdgcn_s_barrier();                                       \
        asm volatile("" ::: "memory");                                      \
    } while (0)

    // prologue: stage tiles 0,1,2 -> slots 0,1,2 (12 gloads, tile-FIFO);
    // vmcnt(8) retires tile 0; barrier makes it collectively visible.
    STAGE(0, 0);
    STAGE(1, 1);
    STAGE(2, 2);
    asm volatile("s_waitcnt vmcnt(8)" ::: "memory");
    __builtin_amdgcn_s_barrier();
    asm volatile("" ::: "memory");

    // main loop: t = 4g..4g+3, g = 0..30 (stages tiles 3..126)
    for (int g = 0; g < NT / 4 - 1; ++g) {
        const int t = g * 4;
        TILE(0, 3, 8, true, t + 3);
        TILE(1, 0, 8, true, t + 4);
        TILE(2, 1, 8, true, t + 5);
        TILE(3, 2, 8, true, t + 6);
    }
    // tail t=124..127: t=124 stages 127; vm ladder 8, 4, 0, 0
    TILE(0, 3, 8, true, 127);
    TILE(1, 0, 4, false, 0);
    TILE(2, 1, 0, false, 0);
    TILE(3, 2, 0, false, 0);

#undef TILE
#undef STAGE
#undef SAp
#undef SBq

    // C/D layout: col = lane&15, row = quad*4 + reg  [verified m89/m91]
#pragma unroll
    for (int mi = 0; mi < 8; ++mi) {
        const int row = m0 + wm * 128 + mi * 16 + quad * 4;
#pragma unroll
        for (int ni = 0; ni < 4; ++ni) {
            const int col = n0 + wn * 64 + ni * 16 + r;
            float* p = C + (size_t)row * NDIM + col;
#pragma unroll
            for (int rr = 0; rr < 4; ++rr)
                p[(size_t)rr * NDIM] = acc[mi][ni][rr];
        }
    }
}

// ---------------------------------------------------------------------------
extern "C" void kernel_launch(void* const* d_in, const int* in_sizes, int n_in,
                              void* d_out, int out_size, void* d_ws, size_t ws_size,
                              hipStream_t stream) {
    const float* A = (const float*)d_in[0];   // [8,1024,4096] == [8192,4096]
    const float* W = (const float*)d_in[1];   // [4096,4096]  (N,K)
    float* out = (float*)d_out;               // [8192,4096] fp32

    unsigned short* Abf = (unsigned short*)d_ws;                       // 64 MiB
    unsigned short* Wbf = Abf + (size_t)M_TOTAL * KDIM;                // 32 MiB

    const long nA = (long)M_TOTAL * KDIM;     // 33,554,432
    const long nW = (long)NDIM * KDIM;        // 16,777,216
    const long nTot = nA + nW;

    cvt_both<<<(int)(nTot / 8 / 256), 256, 0, stream>>>(A, Abf, nA, W, Wbf);

    // 128 KiB dynamic LDS needs the attribute raised once (host-side call,
    // graph-capture safe: not a stream op)
    static bool attr_done = false;
    if (!attr_done) {
        hipFuncSetAttribute((const void*)gemm_bt,
                            hipFuncAttributeMaxDynamicSharedMemorySize, 128 * 1024);
        attr_done = true;
    }

    dim3 grid(NDIM / BN, M_TOTAL / BM);       // (16, 32) = 512 blocks
    gemm_bt<<<grid, 512, 128 * 1024, stream>>>(Abf, Wbf, out);
}